// Round 3
// baseline (184.472 us; speedup 1.0000x reference)
//
#include <hip/hip_runtime.h>
#include <hip/hip_bf16.h>
#include <stdint.h>

typedef unsigned short u16;
typedef __attribute__((ext_vector_type(8))) short short8;
typedef __attribute__((ext_vector_type(4))) float floatx4;

#define N_IMG 4
#define C_IN  2048
#define HW    1024
#define KK    9
#define O_OUT 256
#define NPIX  4096          // N_IMG*HW
#define M_ROWS 2385         // 2304 proj rows + 81 conv rows
#define M_PAD  2432         // 19*128
#define K_DIM  2048
#define BN_EPS 1e-5f

// workspace offsets (bytes), all 256-aligned
#define OFF_A    0u
#define OFF_XT   9961472u          // A: 2432*2048*2
#define OFF_H    26738688u         // XT: 4096*2048*2
#define OFF_SRAW 46661632u         // H: 2432*4096*2
#define OFF_SIG  46809088u         // sraw: 36864*4
#define OFF_STAT 46956544u         // sig: 36864*4

// fp32 -> bf16 bits, round-to-nearest-even
__device__ __forceinline__ u16 f2b(float f) {
    unsigned u = __float_as_uint(f);
    return (u16)((u + 0x7FFFu + ((u >> 16) & 1u)) >> 16);
}

// load 8 consecutive fp32 elements (eidx multiple of 8) as bf16 bits
__device__ __forceinline__ void load8f(const float* base, size_t eidx, u16* out) {
    const float* p = base + eidx;
    float4 a = ((const float4*)p)[0];
    float4 b = ((const float4*)p)[1];
    float f[8] = {a.x, a.y, a.z, a.w, b.x, b.y, b.z, b.w};
#pragma unroll
    for (int j = 0; j < 8; ++j) out[j] = f2b(f[j]);
}

// ---------------- transpose x (N,C,H,W) fp32 -> XT (n*HW+p, c) bf16 ----------------
__global__ void build_xt(const float* __restrict__ x, u16* __restrict__ xt) {
    __shared__ __align__(16) u16 lds[64 * 72];
    int c0 = blockIdx.x * 64, p0 = blockIdx.y * 64, n = blockIdx.z;
    int t = threadIdx.x;
    int r = t >> 3, pv = (t & 7) * 8;
    u16 h0[8], h1[8];
    load8f(x, (size_t)(n * C_IN + c0 + r) * HW + p0 + pv, h0);
    load8f(x, (size_t)(n * C_IN + c0 + r + 32) * HW + p0 + pv, h1);
#pragma unroll
    for (int j = 0; j < 8; ++j) {
        lds[(pv + j) * 72 + r]      = h0[j];
        lds[(pv + j) * 72 + r + 32] = h1[j];
    }
    __syncthreads();
    int pr = t >> 3, cv = (t & 7) * 8;
    uint4 o0 = *(const uint4*)&lds[pr * 72 + cv];
    uint4 o1 = *(const uint4*)&lds[(pr + 32) * 72 + cv];
    *(uint4*)(xt + (size_t)(n * HW + p0 + pr) * K_DIM + c0 + cv) = o0;
    *(uint4*)(xt + (size_t)(n * HW + p0 + pr + 32) * K_DIM + c0 + cv) = o1;
}

// ---------------- build A (M_PAD x K) bf16: rows l*256+o = weight[o,:,l]; rows 2304+k*9+l = conv_w[l,:,k] ----------------
__global__ void build_a(const float* __restrict__ wgt, const float* __restrict__ cw,
                        u16* __restrict__ A, float* __restrict__ stats) {
    __shared__ __align__(16) u16 lds[9 * 2056];
    int b = blockIdx.x, t = threadIdx.x;
    if (b < 256) {
        size_t base = (size_t)b * 18432;   // weight[o][c][l], e = c*9+l
        for (int i = 0; i < 9; ++i) {
            int e0 = (t + i * 256) * 8;
            u16 hv[8];
            load8f(wgt, base + e0, hv);
#pragma unroll
            for (int j = 0; j < 8; ++j) {
                int e = e0 + j;
                int c = e / 9, l = e - c * 9;
                lds[l * 2056 + c] = hv[j];
            }
        }
        __syncthreads();
        for (int l = 0; l < 9; ++l) {
            size_t row = (size_t)l * 256 + b;
            *(uint4*)(A + row * K_DIM + t * 8) = *(const uint4*)&lds[l * 2056 + t * 8];
        }
    } else if (b < 265) {
        int l = b - 256;
        size_t base = (size_t)l * 18432;    // conv_w[l][c][k], e = c*9+k
        for (int i = 0; i < 9; ++i) {
            int e0 = (t + i * 256) * 8;
            u16 hv[8];
            load8f(cw, base + e0, hv);
#pragma unroll
            for (int j = 0; j < 8; ++j) {
                int e = e0 + j;
                int c = e / 9, k = e - c * 9;
                lds[k * 2056 + c] = hv[j];
            }
        }
        __syncthreads();
        for (int k = 0; k < 9; ++k) {
            size_t row = 2304 + (size_t)k * 9 + l;
            *(uint4*)(A + row * K_DIM + t * 8) = *(const uint4*)&lds[k * 2056 + t * 8];
        }
    } else {
        // zero pad rows 2385..2431 and the stats buffer
        uint4 z = {0, 0, 0, 0};
        uint4* dst = (uint4*)(A + (size_t)2385 * K_DIM);
        for (int i = t; i < (47 * 2048) / 8; i += 256) dst[i] = z;
        if (t < 18) stats[t] = 0.0f;
    }
}

// ---------------- GEMM: H (M_PAD x NPIX) = A * XT^T, bf16 in, fp32 acc, bf16 out ----------------
__device__ __forceinline__ void gload_lds16(const void* g, void* l) {
    __builtin_amdgcn_global_load_lds((__attribute__((address_space(1))) void*)(g),
                                     (__attribute__((address_space(3))) void*)(l), 16, 0, 0);
}

__global__ void gemm_bt(const u16* __restrict__ A, const u16* __restrict__ B,
                        __hip_bfloat16* __restrict__ C) {
    __shared__ __align__(16) u16 As[128 * 32];
    __shared__ __align__(16) u16 Bs[128 * 32];
    int bx = blockIdx.x;
    int mt = bx % 19, nt = bx / 19;
    int m0 = mt * 128, n0 = nt * 128;
    int t = threadIdx.x;
    int w = t >> 6, lam = t & 63;
    int wm = w >> 1, wn = w & 1;
    int lm = lam & 15, q = lam >> 4;

    floatx4 acc[4][4];
    floatx4 z = {0.f, 0.f, 0.f, 0.f};
#pragma unroll
    for (int i = 0; i < 4; ++i)
#pragma unroll
        for (int j = 0; j < 4; ++j) acc[i][j] = z;

    int c0 = w, c1 = w + 4;                 // LDS chunk ids (wave-uniform)
    int rrow0 = c0 * 16 + (lam >> 2);
    int rrow1 = c1 * 16 + (lam >> 2);
    int kc = (lam & 3) * 8;
    const u16* gA0 = A + (size_t)(m0 + rrow0) * K_DIM + kc;
    const u16* gA1 = A + (size_t)(m0 + rrow1) * K_DIM + kc;
    const u16* gB0 = B + (size_t)(n0 + rrow0) * K_DIM + kc;
    const u16* gB1 = B + (size_t)(n0 + rrow1) * K_DIM + kc;
    u16* lA0 = As + c0 * 512;  u16* lA1 = As + c1 * 512;
    u16* lB0 = Bs + c0 * 512;  u16* lB1 = Bs + c1 * 512;

    for (int kt = 0; kt < K_DIM / 32; ++kt) {
        gload_lds16(gA0, lA0);
        gload_lds16(gA1, lA1);
        gload_lds16(gB0, lB0);
        gload_lds16(gB1, lB1);
        gA0 += 32; gA1 += 32; gB0 += 32; gB1 += 32;
        __syncthreads();
        short8 af[4], bf[4];
#pragma unroll
        for (int i = 0; i < 4; ++i)
            af[i] = *(const short8*)(As + (wm * 64 + i * 16 + lm) * 32 + q * 8);
#pragma unroll
        for (int j = 0; j < 4; ++j)
            bf[j] = *(const short8*)(Bs + (wn * 64 + j * 16 + lm) * 32 + q * 8);
#pragma unroll
        for (int i = 0; i < 4; ++i)
#pragma unroll
            for (int j = 0; j < 4; ++j)
                acc[i][j] = __builtin_amdgcn_mfma_f32_16x16x32_bf16(af[i], bf[j], acc[i][j], 0, 0, 0);
        __syncthreads();
    }
    // C/D layout: col=lane&15, row=(lane>>4)*4+reg
#pragma unroll
    for (int i = 0; i < 4; ++i) {
        int gm = m0 + wm * 64 + i * 16 + q * 4;
#pragma unroll
        for (int j = 0; j < 4; ++j) {
            int gn = n0 + wn * 64 + j * 16 + lm;
#pragma unroll
            for (int r = 0; r < 4; ++r)
                C[(size_t)(gm + r) * NPIX + gn] = __float2bfloat16(acc[i][j][r]);
        }
    }
}

// ---------------- sigma_raw (conv via shifted conv rows of H) + BN stats ----------------
__global__ void sigma_stats(const __hip_bfloat16* __restrict__ Hm, float* __restrict__ sraw,
                            float* __restrict__ stats) {
    int b = blockIdx.x;           // n*9 + l
    int n = b / 9, l = b - n * 9;
    int t = threadIdx.x;
    float s1 = 0.f, s2 = 0.f;
    for (int i = 0; i < 4; ++i) {
        int pix = t + i * 256;
        int y = pix >> 5, x = pix & 31;
        float v = 0.f;
#pragma unroll
        for (int k = 0; k < 9; ++k) {
            int yy = y + k / 3 - 1, xx = x + (k % 3) - 1;
            if (yy >= 0 && yy < 32 && xx >= 0 && xx < 32)
                v += __bfloat162float(Hm[(size_t)(2304 + k * 9 + l) * NPIX + n * HW + yy * 32 + xx]);
        }
        sraw[(size_t)b * HW + pix] = v;
        s1 += v; s2 += v * v;
    }
    __shared__ float r1[256], r2[256];
    r1[t] = s1; r2[t] = s2;
    __syncthreads();
    for (int s = 128; s > 0; s >>= 1) {
        if (t < s) { r1[t] += r1[t + s]; r2[t] += r2[t + s]; }
        __syncthreads();
    }
    if (t == 0) { atomicAdd(&stats[l], r1[0]); atomicAdd(&stats[9 + l], r2[0]); }
}

// ---------------- BN (train-mode, biased var) + softmax over 9 kernel positions ----------------
__global__ void bn_softmax(const float* __restrict__ sraw, const float* __restrict__ stats,
                           const float* __restrict__ gamma, const float* __restrict__ beta,
                           float* __restrict__ sig) {
    int gid = blockIdx.x * 256 + threadIdx.x;   // 0..4095
    int n = gid >> 10, pix = gid & 1023;
    float v[9];
    float mx = -1e30f;
#pragma unroll
    for (int l = 0; l < 9; ++l) {
        float mean = stats[l] * (1.f / 4096.f);
        float var  = stats[9 + l] * (1.f / 4096.f) - mean * mean;
        float tv = (sraw[(size_t)(n * 9 + l) * HW + pix] - mean) * rsqrtf(var + BN_EPS);
        tv = tv * gamma[l] + beta[l];
        v[l] = tv; mx = fmaxf(mx, tv);
    }
    float s = 0.f;
#pragma unroll
    for (int l = 0; l < 9; ++l) { v[l] = __expf(v[l] - mx); s += v[l]; }
    float inv = 1.f / s;
#pragma unroll
    for (int l = 0; l < 9; ++l) sig[(size_t)(n * 9 + l) * HW + pix] = v[l] * inv;
}

// ---------------- epilogue: out[n,o,pix] = sum_l sig[n,l,pix] * H[l*256+o, shifted pix], fp32 out ----------------
__global__ void epilogue(const __hip_bfloat16* __restrict__ Hm, const float* __restrict__ sig,
                         float* __restrict__ out) {
    int b = blockIdx.x;           // n*256 + o
    int n = b >> 8, o = b & 255;
    int t = threadIdx.x;
    for (int i = 0; i < 4; ++i) {
        int pix = t + i * 256;
        int y = pix >> 5, x = pix & 31;
        float acc = 0.f;
#pragma unroll
        for (int l = 0; l < 9; ++l) {
            int yy = y + l / 3 - 1, xx = x + (l % 3) - 1;
            if (yy >= 0 && yy < 32 && xx >= 0 && xx < 32) {
                float s = sig[(size_t)(n * 9 + l) * HW + pix];
                float h = __bfloat162float(Hm[(size_t)(l * 256 + o) * NPIX + n * HW + yy * 32 + xx]);
                acc += s * h;
            }
        }
        out[(size_t)b * HW + pix] = acc;
    }
}

extern "C" void kernel_launch(void* const* d_in, const int* in_sizes, int n_in,
                              void* d_out, int out_size, void* d_ws, size_t ws_size,
                              hipStream_t stream) {
    const float* x     = (const float*)d_in[0];
    const float* cw    = (const float*)d_in[1];
    const float* gamma = (const float*)d_in[2];
    const float* beta  = (const float*)d_in[3];
    const float* wgt   = (const float*)d_in[4];

    char* ws = (char*)d_ws;
    u16*   Abuf = (u16*)(ws + OFF_A);
    u16*   XT   = (u16*)(ws + OFF_XT);
    u16*   Hm   = (u16*)(ws + OFF_H);
    float* sraw = (float*)(ws + OFF_SRAW);
    float* sig  = (float*)(ws + OFF_SIG);
    float* stats= (float*)(ws + OFF_STAT);

    build_xt<<<dim3(C_IN / 64, HW / 64, N_IMG), 256, 0, stream>>>(x, XT);
    build_a<<<266, 256, 0, stream>>>(wgt, cw, Abuf, stats);
    gemm_bt<<<(M_PAD / 128) * (NPIX / 128), 256, 0, stream>>>(Abuf, XT, (__hip_bfloat16*)Hm);
    sigma_stats<<<N_IMG * KK, 256, 0, stream>>>((const __hip_bfloat16*)Hm, sraw, stats);
    bn_softmax<<<16, 256, 0, stream>>>(sraw, stats, gamma, beta, sig);
    epilogue<<<N_IMG * O_OUT, 256, 0, stream>>>((const __hip_bfloat16*)Hm, sig, (float*)d_out);
}